// Round 15
// baseline (714.938 us; speedup 1.0000x reference)
//
#include <hip/hip_runtime.h>
#include <stdint.h>

typedef short s16x8 __attribute__((ext_vector_type(8)));
typedef float f32x4 __attribute__((ext_vector_type(4)));
typedef unsigned u32x2 __attribute__((ext_vector_type(2)));

__device__ __forceinline__ unsigned short f2bf(float f) {
  unsigned u = __builtin_bit_cast(unsigned, f);
  u = (u + 0x7FFFu + ((u >> 16) & 1u)) >> 16;
  return (unsigned short)u;
}
__device__ __forceinline__ float bflo(unsigned u) {   // low bf16 -> f32
  return __builtin_bit_cast(float, u << 16);
}
__device__ __forceinline__ float bfhi(unsigned u) {   // high bf16 -> f32
  return __builtin_bit_cast(float, u & 0xFFFF0000u);
}

__device__ __forceinline__ void gload_lds16(const void* g, void* l) {
  __builtin_amdgcn_global_load_lds((__attribute__((address_space(1))) void*)g,
                                   (__attribute__((address_space(3))) void*)l,
                                   16, 0, 0);
}

// ---- merged prep: [0,11520) convw, [11520,13248) transpose, [13248,13257) biascomb
__global__ __launch_bounds__(256)
void mstr_prep(const float* __restrict__ qw, const float* __restrict__ kw,
               const float* __restrict__ vw, const float* __restrict__ inw,
               const float* __restrict__ mow, const float* __restrict__ ow,
               const float* __restrict__ inb, const float* __restrict__ qb,
               const float* __restrict__ kb, const float* __restrict__ vb,
               unsigned short* __restrict__ inwB, unsigned short* __restrict__ wT,
               unsigned short* __restrict__ mowB, unsigned short* __restrict__ owB,
               float* __restrict__ bc, float* __restrict__ zb)
{
  const long n1 = 589824;
  __shared__ float tile[32][33];
  int b = blockIdx.x, tid = threadIdx.x;
  if (b < 11520) {
    long i = (long)b * 256 + tid;          // < 5*n1
    if (i < 3 * n1)      inwB[i] = f2bf(inw[i]);
    else if (i < 4 * n1) mowB[i - 3 * n1] = f2bf(mow[i - 3 * n1]);
    else                 owB[i - 4 * n1] = f2bf(ow[i - 4 * n1]);
  } else if (b < 13248) {
    int z = b - 11520;
    int s = z % 3, r = z / 3;
    int jb = r % 24, kb = r / 24;
    const float* src = (s == 0) ? qw : (s == 1) ? kw : vw;
    unsigned short* dst = wT + (long)s * n1;
    int tx = tid & 31, ty = tid >> 5;
    int j0 = jb * 32, k0 = kb * 32;
#pragma unroll
    for (int i = 0; i < 4; ++i)
      tile[ty + i * 8][tx] = src[(long)(j0 + ty + i * 8) * 768 + k0 + tx];
    __syncthreads();
#pragma unroll
    for (int i = 0; i < 4; ++i)
      dst[(long)(k0 + ty + i * 8) * 768 + j0 + tx] = f2bf(tile[tx][ty + i * 8]);
  } else {
    int gid = (b - 13248) * 256 + tid;     // < 2304
    if (gid < 768) zb[gid] = 0.f;
    int s = gid / 768, c = gid - s * 768;
    const float* bb = (s == 0) ? qb : (s == 1) ? kb : vb;
    const float* wrow = inw + (long)(s * 768 + c) * 768;
    float a = inb[s * 768 + c];
    for (int j = 0; j < 768; ++j) a += bb[j] * wrow[j];
    bc[gid] = a;
  }
}

// ---- LayerNorm: g*4095 rows (skips t=4095 per batch), bf16 out (nt stores) ----
__global__ __launch_bounds__(256)
void mstr_ln(const float* __restrict__ x, const float* __restrict__ g,
             const float* __restrict__ bt, unsigned short* __restrict__ xn)
{
  int blk = blockIdx.x;
  int bb = blk / 4095, t = blk - bb * 4095;
  const float* xr = x + ((long)bb * 4096 + t) * 768;
  unsigned short* orow = xn + (long)blk * 768;
  int tid = threadIdx.x;
  float v0 = xr[tid], v1 = xr[tid + 256], v2 = xr[tid + 512];
  float s = v0 + v1 + v2;
  float s2 = v0 * v0 + v1 * v1 + v2 * v2;
#pragma unroll
  for (int o = 32; o > 0; o >>= 1) { s += __shfl_down(s, o, 64); s2 += __shfl_down(s2, o, 64); }
  __shared__ float rs[4], rq[4];
  int lane = tid & 63, wid = tid >> 6;
  if (lane == 0) { rs[wid] = s; rq[wid] = s2; }
  __syncthreads();
  float S = rs[0] + rs[1] + rs[2] + rs[3];
  float S2 = rq[0] + rq[1] + rq[2] + rq[3];
  float mu = S * (1.0f / 768.0f);
  float var = S2 * (1.0f / 768.0f) - mu * mu;
  float rstd = rsqrtf(var + 1e-5f);
  __builtin_nontemporal_store(f2bf((v0 - mu) * rstd * g[tid] + bt[tid]), &orow[tid]);
  __builtin_nontemporal_store(f2bf((v1 - mu) * rstd * g[tid + 256] + bt[tid + 256]), &orow[tid + 256]);
  __builtin_nontemporal_store(f2bf((v2 - mu) * rstd * g[tid + 512] + bt[tid + 512]), &orow[tid + 512]);
}

// ---- bf16 MFMA GEMM, 3-buffer pipeline (BK=32, counted vmcnt(4), 1 barrier/K-step).
//   r9 core (best measured). C[gr', cs] = sum_k A[gr,k] W[c,k] + bias[c]; K=768.
//   zoff: per-blockIdx.y element offset applied to A, W, outs (merged wprep).
//   EPI 0: bf16 out (nt), segment routing, row remap gr'=(gr/rowDiv)*rowStride+gr%rowDiv.
//   EPI 1: f32 out + xadd residual (identity rows), nt load+store.
//   EPI 2: bf16 out with exact GELU (nt), row remap.
//   LDS swizzle: global source chunk pre-XOR'd with ((row>>1)&3); read XORs back.
template<int EPI>
__global__ __launch_bounds__(256, 4)
void mstr_gemm(const unsigned short* __restrict__ A, int M,
               const unsigned short* __restrict__ W,
               const float* __restrict__ bias,
               unsigned short* out0, unsigned short* out1, unsigned short* out2,
               float* outf, const float* xadd,
               int rowDiv, int rowStride, int NC, int nwg, long zoff)
{
  __shared__ char smem[49152];   // 3 buffers x (A 8KB + B 8KB)
  if (zoff) {
    long zo = (long)blockIdx.y * zoff;
    A += zo; W += zo; out0 += zo; out1 += zo; out2 += zo;
  }
  // bijective XCD swizzle (m204)
  int orig = blockIdx.x;
  int swq = nwg >> 3, swr = nwg & 7;
  int xcd = orig & 7, sidx = orig >> 3;
  int wg = (xcd < swr ? xcd * (swq + 1) : swr * (swq + 1) + (xcd - swr) * swq) + sidx;
  int rowp = wg / NC, colp = wg - rowp * NC;

  const int tid = threadIdx.x;
  const int lane = tid & 63;
  const int wid = tid >> 6;
  const int wr = wid >> 1, wc = wid & 1;
  const long row0 = (long)rowp * 128;
  const int col0 = colp * 128;

  // staging: thread tid covers LDS row sr (and sr+64), swizzled chunk sc
  const int sr = tid >> 2;
  const int sc = (((tid & 3) ^ ((tid >> 3) & 3)) << 3);   // elems
  long a0r = row0 + sr;       if (a0r >= M) a0r = M - 1;
  long a1r = row0 + sr + 64;  if (a1r >= M) a1r = M - 1;
  const unsigned short* Ag0 = A + a0r * 768 + sc;
  const unsigned short* Ag1 = A + a1r * 768 + sc;
  const unsigned short* Bg0 = W + (long)(col0 + sr) * 768 + sc;
  const unsigned short* Bg1 = W + (long)(col0 + sr + 64) * 768 + sc;
  char* ldsT = smem + tid * 16;

  // fragment-read offsets (per-lane constants)
  const int fr = lane & 15;
  const int g4 = lane >> 4;                       // k-chunk 0..3
  const int cx = ((g4 ^ ((fr >> 1) & 3)) << 4);   // swizzled chunk bytes
  const int aoff = (wr * 64 + fr) * 64 + cx;      // + m*1024 + buf offset
  const int boff = 8192 + (wc * 64 + fr) * 64 + cx;

  f32x4 acc[4][4] = {};

#define MSTAGE(T, BO) { int kk_ = (T) * 32; \
    gload_lds16(Ag0 + kk_, ldsT + (BO)); \
    gload_lds16(Ag1 + kk_, ldsT + (BO) + 4096); \
    gload_lds16(Bg0 + kk_, ldsT + (BO) + 8192); \
    gload_lds16(Bg1 + kk_, ldsT + (BO) + 12288); }

  MSTAGE(0, 0)
  int stBo = 16384;   // buffer offset for next stage
  int rdBo = 0;       // buffer offset for current compute
  for (int t = 0; t < 24; ++t) {
    if (t < 23) {
      MSTAGE(t + 1, stBo)
      stBo += 16384; if (stBo == 49152) stBo = 0;
      asm volatile("s_waitcnt vmcnt(4)" ::: "memory");   // stage(t) landed
    } else {
      asm volatile("s_waitcnt vmcnt(0)" ::: "memory");
    }
    __builtin_amdgcn_s_barrier();
    const int bo = rdBo;
    rdBo += 16384; if (rdBo == 49152) rdBo = 0;
    s16x8 af[4], bfv[4];
#pragma unroll
    for (int m = 0; m < 4; ++m) af[m] = *(const s16x8*)(smem + bo + aoff + m * 1024);
#pragma unroll
    for (int n = 0; n < 4; ++n) bfv[n] = *(const s16x8*)(smem + bo + boff + n * 1024);
    __builtin_amdgcn_s_setprio(1);
#pragma unroll
    for (int m = 0; m < 4; ++m)
#pragma unroll
      for (int n = 0; n < 4; ++n)
        acc[m][n] = __builtin_amdgcn_mfma_f32_16x16x32_bf16(af[m], bfv[n], acc[m][n], 0, 0, 0);
    __builtin_amdgcn_s_setprio(0);
  }
#undef MSTAGE

  int seg = (col0 >= 1536) ? 2 : (col0 >= 768 ? 1 : 0);
  unsigned short* outp = (seg == 0) ? out0 : (seg == 1) ? out1 : out2;
  int csub = seg * 768;
#pragma unroll
  for (int m = 0; m < 4; ++m) {
#pragma unroll
    for (int r = 0; r < 4; ++r) {
      long gr = row0 + wr * 64 + m * 16 + g4 * 4 + r;
      if (gr < M) {
        long orow;
        if (EPI == 1) {
          orow = gr;
        } else {
          int qq = (int)gr / rowDiv;
          orow = (long)qq * rowStride + ((int)gr - qq * rowDiv);
        }
#pragma unroll
        for (int n = 0; n < 4; ++n) {
          int c = col0 + wc * 64 + n * 16 + fr;
          float v = acc[m][n][r] + bias[c];
          if (EPI == 1) {
            long o = gr * 768 + c;
            __builtin_nontemporal_store(v + __builtin_nontemporal_load(&xadd[o]), &outf[o]);
          } else if (EPI == 2) {
            v = 0.5f * v * (1.0f + erff(v * 0.70710678118654752f));
            __builtin_nontemporal_store(f2bf(v), &outp[orow * 768 + (c - csub)]);
          } else {
            __builtin_nontemporal_store(f2bf(v), &outp[orow * 768 + (c - csub)]);
          }
        }
      }
    }
  }
}

// ---- merged flat pooling: one launch, all 3 levels (mean of 3 / 9 / 27
//      scale-0 rows — exactly the reference's pooling structure).
__global__ __launch_bounds__(384)
void mstr_pool(unsigned short* qp, unsigned short* kp, unsigned short* vp)
{
  unsigned short* p = (blockIdx.y == 0) ? qp : (blockIdx.y == 1) ? kp : vp;
  int tok = blockIdx.x;              // 0 .. g*1968-1
  int bb = tok / 1968, r = tok - bb * 1968;
  int j, F, dstOff;
  if (r < 1365)      { j = r;        F = 3;  dstOff = 4095; }
  else if (r < 1818) { j = r - 1365; F = 9;  dstOff = 5460; }
  else               { j = r - 1818; F = 27; dstOff = 5913; }
  long srcB = ((long)bb * 6063 + (long)j * F) * 768 + threadIdx.x * 2;
  long dstB = ((long)bb * 6063 + dstOff + j) * 768 + threadIdx.x * 2;
  float lo = 0.f, hi = 0.f;
  for (int i = 0; i < F; ++i) {
    unsigned u = *(const unsigned*)(p + srcB + (long)i * 768);
    lo += bflo(u); hi += bfhi(u);
  }
  float inv = 1.0f / (float)F;
  unsigned o = (unsigned)f2bf(lo * inv) | ((unsigned)f2bf(hi * inv) << 16);
  *(unsigned*)(p + dstB) = o;
}

// ---- 3x3 window attention, one wave per (window, head); writes in-place to qp
__global__ __launch_bounds__(256)
void mstr_attn(unsigned short* qp, unsigned short* kp, unsigned short* vp, int nwaves)
{
  int gw = blockIdx.x * 4 + (threadIdx.x >> 6);
  if (gw >= nwaves) return;
  int lane = threadIdx.x & 63;
  int win = gw / 6, h = gw - win * 6;
  int bb = win / 2021, ww = win - bb * 2021;
  int row0;
  if (ww < 1365)      row0 = 3 * ww;
  else if (ww < 1820) row0 = 4095 + 3 * (ww - 1365);
  else if (ww < 1971) row0 = 5460 + 3 * (ww - 1820);
  else                row0 = 5913 + 3 * (ww - 1971);
  long base = ((long)bb * 6063 + row0) * 768 + h * 128 + lane * 2;
  float q[3][2], k[3][2], v[3][2];
#pragma unroll
  for (int i = 0; i < 3; ++i) {
    unsigned uq = *(const unsigned*)(qp + base + i * 768);
    unsigned uk = *(const unsigned*)(kp + base + i * 768);
    unsigned uv = *(const unsigned*)(vp + base + i * 768);
    q[i][0] = bflo(uq); q[i][1] = bfhi(uq);
    k[i][0] = bflo(uk); k[i][1] = bfhi(uk);
    v[i][0] = bflo(uv); v[i][1] = bfhi(uv);
  }
  float s[3][3];
#pragma unroll
  for (int i = 0; i < 3; ++i)
#pragma unroll
    for (int j = 0; j < 3; ++j)
      s[i][j] = q[i][0] * k[j][0] + q[i][1] * k[j][1];
#pragma unroll
  for (int st = 1; st < 64; st <<= 1) {
#pragma unroll
    for (int i = 0; i < 3; ++i)
#pragma unroll
      for (int j = 0; j < 3; ++j)
        s[i][j] += __shfl_xor(s[i][j], st, 64);
  }
  const float scl = 0.088388347648318447f;   // 1/sqrt(128)
#pragma unroll
  for (int i = 0; i < 3; ++i) {
    float s0 = s[i][0] * scl, s1 = s[i][1] * scl, s2 = s[i][2] * scl;
    float m = fmaxf(s0, fmaxf(s1, s2));
    float e0 = __expf(s0 - m), e1 = __expf(s1 - m), e2 = __expf(s2 - m);
    float inv = 1.0f / (e0 + e1 + e2);
    e0 *= inv; e1 *= inv; e2 *= inv;
    float o0 = e0 * v[0][0] + e1 * v[1][0] + e2 * v[2][0];
    float o1 = e0 * v[0][1] + e1 * v[1][1] + e2 * v[2][1];
    unsigned o = (unsigned)f2bf(o0) | ((unsigned)f2bf(o1) << 16);
    *(unsigned*)(qp + base + i * 768) = o;
  }
}

// ---- gather-upsample + sum over 4 scales (GELU applied in mo epilogue).
//      8B-wide: each thread handles 4 columns.
__global__ __launch_bounds__(256)
void mstr_gelusum(const unsigned short* __restrict__ omo, unsigned short* __restrict__ acc)
{
  long gid = (long)blockIdx.x * 256 + threadIdx.x;   // < g*4096*192
  int d4 = (int)(gid % 192);
  long row = gid / 192;                              // bb*4096 + t
  int bb = (int)(row >> 12);
  int t = (int)(row & 4095);
  const int NkA[4] = {4095, 1365, 453, 150};
  const int soA[4] = {0, 4095, 5460, 5913};
  float a0 = 0.f, a1 = 0.f, a2 = 0.f, a3 = 0.f;
#pragma unroll
  for (int kk = 0; kk < 4; ++kk) {
    int idx = (t * NkA[kk]) >> 12;
    long tok = (long)bb * 6063 + soA[kk] + idx;
    u32x2 u = *(const u32x2*)(omo + tok * 768 + d4 * 4);
    a0 += bflo(u.x); a1 += bfhi(u.x);
    a2 += bflo(u.y); a3 += bfhi(u.y);
  }
  u32x2 o;
  o.x = (unsigned)f2bf(a0) | ((unsigned)f2bf(a1) << 16);
  o.y = (unsigned)f2bf(a2) | ((unsigned)f2bf(a3) << 16);
  __builtin_nontemporal_store(o, (u32x2*)(acc + row * 768 + d4 * 4));
}

extern "C" void kernel_launch(void* const* d_in, const int* in_sizes, int n_in,
                              void* d_out, int out_size, void* d_ws, size_t ws_size,
                              hipStream_t stream)
{
  const float* x   = (const float*)d_in[0];
  const float* lng = (const float*)d_in[1];
  const float* lnb = (const float*)d_in[2];
  const float* qw  = (const float*)d_in[3];
  const float* qb  = (const float*)d_in[4];
  const float* kw  = (const float*)d_in[5];
  const float* kb  = (const float*)d_in[6];
  const float* vw  = (const float*)d_in[7];
  const float* vb  = (const float*)d_in[8];
  const float* inw = (const float*)d_in[9];
  const float* inb = (const float*)d_in[10];
  const float* mob = (const float*)d_in[12];
  const float* ow  = (const float*)d_in[13];
  const float* ob  = (const float*)d_in[14];

  const long n1 = 589824;                 // 768*768
  char* ws = (char*)d_ws;
  size_t off = 0;
  auto alloc = [&](size_t bytes) -> char* {
    char* p = ws + off;
    off += (bytes + 255) & ~(size_t)255;
    return p;
  };
  unsigned short* Wc = (unsigned short*)alloc((size_t)5 * n1 * 2);  // Mq,Mk,Mv,mowB,owB
  float* bc = (float*)alloc(2304 * 4);
  float* zb = (float*)alloc(768 * 4);
  size_t fixed = off;

  // choose largest batch-group size g that fits ws
  int g = 0;
  const int cands[4] = {8, 4, 2, 1};
  for (int ci = 0; ci < 4; ++ci) {
    int c = cands[ci];
    size_t need = fixed + (size_t)c * 4096 * 768 * 2      // xn / acc slot
                + 2 * (size_t)c * 6063 * 768 * 2          // qp, kp
                + 1024;
    if (need <= ws_size) { g = c; break; }
  }
  if (!g) return;

  char* GR = ws + fixed;
  unsigned short* xnacc = (unsigned short*)GR;                   // g*4096 rows
  unsigned short* qp = xnacc + (size_t)g * 4096 * 768;           // g*6063 rows
  unsigned short* kp = qp + (size_t)g * 6063 * 768;              // g*6063 rows
  // staging for weight prep (dead before group 0's LN)
  unsigned short* inwB = (unsigned short*)GR;                    // 3*n1
  unsigned short* wT   = inwB + 3 * n1;                          // 3*n1

  unsigned short* mowB = Wc + 3 * n1;
  unsigned short* owB  = Wc + 4 * n1;

  // ---- weight prep (merged) ----
  mstr_prep<<<dim3(13257), dim3(256), 0, stream>>>(qw, kw, vw, inw, (const float*)d_in[11], ow,
                                                   inb, qb, kb, vb, inwB, wT, mowB, owB, bc, zb);
  mstr_gemm<0><<<dim3(36, 3), dim3(256), 0, stream>>>(inwB, 768, wT, zb, Wc, Wc, Wc,
                                                      nullptr, nullptr, 768, 768, 6, 36, n1);

  // ---- per-group pipeline ----
  int ng = 8 / g;
  for (int gi = 0; gi < ng; ++gi) {
    const float* xg = x + (long)gi * g * 4096 * 768;
    unsigned short* vp = (unsigned short*)d_out + (long)gi * g * 4096 * 768 * 2;  // scratch in d_out
    mstr_ln<<<dim3(g * 4095), dim3(256), 0, stream>>>(xg, lng, lnb, xnacc);
    int M1 = g * 4095, gb1 = (M1 + 127) / 128;
    int nwg1 = gb1 * 18;
    // fused Q/K/V projection: N=2304, segments -> qp/kp/vp with row remap
    mstr_gemm<0><<<dim3(nwg1), dim3(256), 0, stream>>>(xnacc, M1, Wc, bc,
                                                       qp, kp, vp, nullptr, nullptr,
                                                       4095, 6063, 18, nwg1, 0);
    // flat pooling, all levels, one launch
    mstr_pool<<<dim3(g * 1968, 3), dim3(384), 0, stream>>>(qp, kp, vp);
    int nw = g * 2021 * 6;
    mstr_attn<<<dim3((nw + 3) / 4), dim3(256), 0, stream>>>(qp, kp, vp, nw);
    int M2 = g * 6063;
    int nwg2 = ((M2 + 127) / 128) * 6;
    // mo projection with fused exact GELU in epilogue
    mstr_gemm<2><<<dim3(nwg2), dim3(256), 0, stream>>>(qp, M2, mowB, mob, kp, kp, kp,
                                                       nullptr, nullptr, M2, 0, 6, nwg2, 0);
    mstr_gelusum<<<dim3(g * 3072), dim3(256), 0, stream>>>(kp, xnacc);
    int M3 = g * 4096;
    int nwg3 = (M3 / 128) * 6;
    mstr_gemm<1><<<dim3(nwg3), dim3(256), 0, stream>>>(xnacc, M3, owB, ob, nullptr, nullptr, nullptr,
                                                       (float*)d_out + (long)gi * g * 4096 * 768, xg,
                                                       M3, 0, 6, nwg3, 0);
  }
}

// Round 16
// 623.972 us; speedup vs baseline: 1.1458x; 1.1458x over previous
//
#include <hip/hip_runtime.h>
#include <stdint.h>

typedef short s16x8 __attribute__((ext_vector_type(8)));
typedef float f32x4 __attribute__((ext_vector_type(4)));

__device__ __forceinline__ unsigned short f2bf(float f) {
  unsigned u = __builtin_bit_cast(unsigned, f);
  u = (u + 0x7FFFu + ((u >> 16) & 1u)) >> 16;
  return (unsigned short)u;
}
__device__ __forceinline__ float bf2f(unsigned short h) {
  unsigned u = ((unsigned)h) << 16;
  return __builtin_bit_cast(float, u);
}

__device__ __forceinline__ void gload_lds16(const void* g, void* l) {
  __builtin_amdgcn_global_load_lds((__attribute__((address_space(1))) void*)g,
                                   (__attribute__((address_space(3))) void*)l,
                                   16, 0, 0);
}

// ---- merged prep: [0,11520) convw, [11520,13248) transpose, [13248,13257) biascomb
__global__ __launch_bounds__(256)
void mstr_prep(const float* __restrict__ qw, const float* __restrict__ kw,
               const float* __restrict__ vw, const float* __restrict__ inw,
               const float* __restrict__ mow, const float* __restrict__ ow,
               const float* __restrict__ inb, const float* __restrict__ qb,
               const float* __restrict__ kb, const float* __restrict__ vb,
               unsigned short* __restrict__ inwB, unsigned short* __restrict__ wT,
               unsigned short* __restrict__ mowB, unsigned short* __restrict__ owB,
               float* __restrict__ bc, float* __restrict__ zb)
{
  const long n1 = 589824;
  __shared__ float tile[32][33];
  int b = blockIdx.x, tid = threadIdx.x;
  if (b < 11520) {
    long i = (long)b * 256 + tid;          // < 5*n1
    if (i < 3 * n1)      inwB[i] = f2bf(inw[i]);
    else if (i < 4 * n1) mowB[i - 3 * n1] = f2bf(mow[i - 3 * n1]);
    else                 owB[i - 4 * n1] = f2bf(ow[i - 4 * n1]);
  } else if (b < 13248) {
    int z = b - 11520;
    int s = z % 3, r = z / 3;
    int jb = r % 24, kb = r / 24;
    const float* src = (s == 0) ? qw : (s == 1) ? kw : vw;
    unsigned short* dst = wT + (long)s * n1;
    int tx = tid & 31, ty = tid >> 5;
    int j0 = jb * 32, k0 = kb * 32;
#pragma unroll
    for (int i = 0; i < 4; ++i)
      tile[ty + i * 8][tx] = src[(long)(j0 + ty + i * 8) * 768 + k0 + tx];
    __syncthreads();
#pragma unroll
    for (int i = 0; i < 4; ++i)
      dst[(long)(k0 + ty + i * 8) * 768 + j0 + tx] = f2bf(tile[tx][ty + i * 8]);
  } else {
    int gid = (b - 13248) * 256 + tid;     // < 2304
    if (gid < 768) zb[gid] = 0.f;
    int s = gid / 768, c = gid - s * 768;
    const float* bb = (s == 0) ? qb : (s == 1) ? kb : vb;
    const float* wrow = inw + (long)(s * 768 + c) * 768;
    float a = inb[s * 768 + c];
    for (int j = 0; j < 768; ++j) a += bb[j] * wrow[j];
    bc[gid] = a;
  }
}

// ---- LayerNorm: g*4095 rows (skips t=4095 per batch), bf16 out (nt stores) ----
__global__ __launch_bounds__(256)
void mstr_ln(const float* __restrict__ x, const float* __restrict__ g,
             const float* __restrict__ bt, unsigned short* __restrict__ xn)
{
  int blk = blockIdx.x;
  int bb = blk / 4095, t = blk - bb * 4095;
  const float* xr = x + ((long)bb * 4096 + t) * 768;
  unsigned short* orow = xn + (long)blk * 768;
  int tid = threadIdx.x;
  float v0 = xr[tid], v1 = xr[tid + 256], v2 = xr[tid + 512];
  float s = v0 + v1 + v2;
  float s2 = v0 * v0 + v1 * v1 + v2 * v2;
#pragma unroll
  for (int o = 32; o > 0; o >>= 1) { s += __shfl_down(s, o, 64); s2 += __shfl_down(s2, o, 64); }
  __shared__ float rs[4], rq[4];
  int lane = tid & 63, wid = tid >> 6;
  if (lane == 0) { rs[wid] = s; rq[wid] = s2; }
  __syncthreads();
  float S = rs[0] + rs[1] + rs[2] + rs[3];
  float S2 = rq[0] + rq[1] + rq[2] + rq[3];
  float mu = S * (1.0f / 768.0f);
  float var = S2 * (1.0f / 768.0f) - mu * mu;
  float rstd = rsqrtf(var + 1e-5f);
  __builtin_nontemporal_store(f2bf((v0 - mu) * rstd * g[tid] + bt[tid]), &orow[tid]);
  __builtin_nontemporal_store(f2bf((v1 - mu) * rstd * g[tid + 256] + bt[tid + 256]), &orow[tid + 256]);
  __builtin_nontemporal_store(f2bf((v2 - mu) * rstd * g[tid + 512] + bt[tid + 512]), &orow[tid + 512]);
}

// ---- bf16 MFMA GEMM: A via 3-buffer LDS pipeline, counted vmcnt(4),
//   1 raw barrier/K-step, 0-conflict swizzle, NT-store epilogue (r9 core).
template<int EPI>
__global__ __launch_bounds__(256, 4)
void mstr_gemm(const unsigned short* __restrict__ A, int M,
               const unsigned short* __restrict__ W,
               const float* __restrict__ bias,
               unsigned short* out0, unsigned short* out1, unsigned short* out2,
               float* outf, const float* xadd,
               int rowDiv, int rowStride, int NC, int nwg, long zoff)
{
  __shared__ char smem[49152];   // 3 buffers x (A 8KB + B 8KB)
  if (zoff) {
    long zo = (long)blockIdx.y * zoff;
    A += zo; W += zo; out0 += zo; out1 += zo; out2 += zo;
  }
  // bijective XCD swizzle (m204)
  int orig = blockIdx.x;
  int swq = nwg >> 3, swr = nwg & 7;
  int xcd = orig & 7, sidx = orig >> 3;
  int wg = (xcd < swr ? xcd * (swq + 1) : swr * (swq + 1) + (xcd - swr) * swq) + sidx;
  int rowp = wg / NC, colp = wg - rowp * NC;

  const int tid = threadIdx.x;
  const int lane = tid & 63;
  const int wid = tid >> 6;
  const int wr = wid >> 1, wc = wid & 1;
  const long row0 = (long)rowp * 128;
  const int col0 = colp * 128;

  const int sr = tid >> 2;
  const int sc = (((tid & 3) ^ ((tid >> 3) & 3)) << 3);   // elems
  long a0r = row0 + sr;       if (a0r >= M) a0r = M - 1;
  long a1r = row0 + sr + 64;  if (a1r >= M) a1r = M - 1;
  const unsigned short* Ag0 = A + a0r * 768 + sc;
  const unsigned short* Ag1 = A + a1r * 768 + sc;
  const unsigned short* Bg0 = W + (long)(col0 + sr) * 768 + sc;
  const unsigned short* Bg1 = W + (long)(col0 + sr + 64) * 768 + sc;
  char* ldsT = smem + tid * 16;

  const int fr = lane & 15;
  const int g4 = lane >> 4;
  const int cx = ((g4 ^ ((fr >> 1) & 3)) << 4);
  const int aoff = (wr * 64 + fr) * 64 + cx;
  const int boff = 8192 + (wc * 64 + fr) * 64 + cx;

  f32x4 acc[4][4] = {};

#define MSTAGE(T, BO) { int kk_ = (T) * 32; \
    gload_lds16(Ag0 + kk_, ldsT + (BO)); \
    gload_lds16(Ag1 + kk_, ldsT + (BO) + 4096); \
    gload_lds16(Bg0 + kk_, ldsT + (BO) + 8192); \
    gload_lds16(Bg1 + kk_, ldsT + (BO) + 12288); }

  MSTAGE(0, 0)
  int stBo = 16384;   // buffer offset for next stage
  int rdBo = 0;       // buffer offset for current compute
  for (int t = 0; t < 24; ++t) {
    if (t < 23) {
      MSTAGE(t + 1, stBo)
      stBo += 16384; if (stBo == 49152) stBo = 0;
      asm volatile("s_waitcnt vmcnt(4)" ::: "memory");   // stage(t) landed
    } else {
      asm volatile("s_waitcnt vmcnt(0)" ::: "memory");
    }
    __builtin_amdgcn_s_barrier();
    const int bo = rdBo;
    rdBo += 16384; if (rdBo == 49152) rdBo = 0;
    s16x8 af[4], bfv[4];
#pragma unroll
    for (int m = 0; m < 4; ++m) af[m] = *(const s16x8*)(smem + bo + aoff + m * 1024);
#pragma unroll
    for (int n = 0; n < 4; ++n) bfv[n] = *(const s16x8*)(smem + bo + boff + n * 1024);
    __builtin_amdgcn_s_setprio(1);
#pragma unroll
    for (int m = 0; m < 4; ++m)
#pragma unroll
      for (int n = 0; n < 4; ++n)
        acc[m][n] = __builtin_amdgcn_mfma_f32_16x16x32_bf16(af[m], bfv[n], acc[m][n], 0, 0, 0);
    __builtin_amdgcn_s_setprio(0);
  }
#undef MSTAGE

  int seg = (col0 >= 1536) ? 2 : (col0 >= 768 ? 1 : 0);
  unsigned short* outp = (seg == 0) ? out0 : (seg == 1) ? out1 : out2;
  int csub = seg * 768;
#pragma unroll
  for (int m = 0; m < 4; ++m) {
#pragma unroll
    for (int r = 0; r < 4; ++r) {
      long gr = row0 + wr * 64 + m * 16 + g4 * 4 + r;
      if (gr < M) {
        long orow;
        if (EPI == 1) {
          orow = gr;
        } else {
          int qq = (int)gr / rowDiv;
          orow = (long)qq * rowStride + ((int)gr - qq * rowDiv);
        }
#pragma unroll
        for (int n = 0; n < 4; ++n) {
          int c = col0 + wc * 64 + n * 16 + fr;
          float v = acc[m][n][r] + bias[c];
          if (EPI == 1) {
            long o = gr * 768 + c;
            __builtin_nontemporal_store(v + xadd[o], &outf[o]);
          } else if (EPI == 2) {
            v = 0.5f * v * (1.0f + erff(v * 0.70710678118654752f));
            __builtin_nontemporal_store(f2bf(v), &outp[orow * 768 + (c - csub)]);
          } else {
            __builtin_nontemporal_store(f2bf(v), &outp[orow * 768 + (c - csub)]);
          }
        }
      }
    }
  }
}

// ---- mean-of-3 pooling within the 6063-token per-batch stream ----
__global__ __launch_bounds__(384)
void mstr_pool(unsigned short* qp, unsigned short* kp, unsigned short* vp,
               int srcOff, int dstOff, int Ndst)
{
  unsigned short* p = (blockIdx.y == 0) ? qp : (blockIdx.y == 1) ? kp : vp;
  int tok = blockIdx.x;
  int bb = tok / Ndst, j = tok - bb * Ndst;
  long sb = ((long)bb * 6063 + srcOff + 3 * j) * 768 + threadIdx.x * 2;
  long db = ((long)bb * 6063 + dstOff + j) * 768 + threadIdx.x * 2;
  unsigned a = *(const unsigned*)(p + sb);
  unsigned b = *(const unsigned*)(p + sb + 768);
  unsigned c = *(const unsigned*)(p + sb + 1536);
  float lo = (bf2f((unsigned short)a) + bf2f((unsigned short)b) + bf2f((unsigned short)c)) * (1.0f / 3.0f);
  float hi = (bf2f((unsigned short)(a >> 16)) + bf2f((unsigned short)(b >> 16)) + bf2f((unsigned short)(c >> 16))) * (1.0f / 3.0f);
  unsigned o = (unsigned)f2bf(lo) | ((unsigned)f2bf(hi) << 16);
  *(unsigned*)(p + db) = o;
}

// ---- 3x3 window attention, one wave per (window, head); writes in-place to qp
__global__ __launch_bounds__(256)
void mstr_attn(unsigned short* qp, unsigned short* kp, unsigned short* vp, int nwaves)
{
  int gw = blockIdx.x * 4 + (threadIdx.x >> 6);
  if (gw >= nwaves) return;
  int lane = threadIdx.x & 63;
  int win = gw / 6, h = gw - win * 6;
  int bb = win / 2021, ww = win - bb * 2021;
  int row0;
  if (ww < 1365)      row0 = 3 * ww;
  else if (ww < 1820) row0 = 4095 + 3 * (ww - 1365);
  else if (ww < 1971) row0 = 5460 + 3 * (ww - 1820);
  else                row0 = 5913 + 3 * (ww - 1971);
  long base = ((long)bb * 6063 + row0) * 768 + h * 128 + lane * 2;
  float q[3][2], k[3][2], v[3][2];
#pragma unroll
  for (int i = 0; i < 3; ++i) {
    unsigned uq = *(const unsigned*)(qp + base + i * 768);
    unsigned uk = *(const unsigned*)(kp + base + i * 768);
    unsigned uv = *(const unsigned*)(vp + base + i * 768);
    q[i][0] = bf2f((unsigned short)uq); q[i][1] = bf2f((unsigned short)(uq >> 16));
    k[i][0] = bf2f((unsigned short)uk); k[i][1] = bf2f((unsigned short)(uk >> 16));
    v[i][0] = bf2f((unsigned short)uv); v[i][1] = bf2f((unsigned short)(uv >> 16));
  }
  float s[3][3];
#pragma unroll
  for (int i = 0; i < 3; ++i)
#pragma unroll
    for (int j = 0; j < 3; ++j)
      s[i][j] = q[i][0] * k[j][0] + q[i][1] * k[j][1];
#pragma unroll
  for (int st = 1; st < 64; st <<= 1) {
#pragma unroll
    for (int i = 0; i < 3; ++i)
#pragma unroll
      for (int j = 0; j < 3; ++j)
        s[i][j] += __shfl_xor(s[i][j], st, 64);
  }
  const float scl = 0.088388347648318447f;   // 1/sqrt(128)
#pragma unroll
  for (int i = 0; i < 3; ++i) {
    float s0 = s[i][0] * scl, s1 = s[i][1] * scl, s2 = s[i][2] * scl;
    float m = fmaxf(s0, fmaxf(s1, s2));
    float e0 = __expf(s0 - m), e1 = __expf(s1 - m), e2 = __expf(s2 - m);
    float inv = 1.0f / (e0 + e1 + e2);
    e0 *= inv; e1 *= inv; e2 *= inv;
    float o0 = e0 * v[0][0] + e1 * v[1][0] + e2 * v[2][0];
    float o1 = e0 * v[0][1] + e1 * v[1][1] + e2 * v[2][1];
    unsigned o = (unsigned)f2bf(o0) | ((unsigned)f2bf(o1) << 16);
    *(unsigned*)(qp + base + i * 768) = o;
  }
}

// ---- gather-upsample + sum over 4 scales (GELU already applied in mo epilogue)
__global__ __launch_bounds__(256)
void mstr_gelusum(const unsigned short* __restrict__ omo, unsigned short* __restrict__ acc)
{
  long gid = (long)blockIdx.x * 256 + threadIdx.x;   // < g*4096*384
  int d2 = (int)(gid % 384);
  long row = gid / 384;                              // bb*4096 + t
  int bb = (int)(row >> 12);
  int t = (int)(row & 4095);
  const int NkA[4] = {4095, 1365, 453, 150};
  const int soA[4] = {0, 4095, 5460, 5913};
  float a0 = 0.f, a1 = 0.f;
#pragma unroll
  for (int kk = 0; kk < 4; ++kk) {
    int idx = (t * NkA[kk]) >> 12;
    long tok = (long)bb * 6063 + soA[kk] + idx;
    unsigned u = *(const unsigned*)(omo + tok * 768 + d2 * 2);
    a0 += bf2f((unsigned short)u);
    a1 += bf2f((unsigned short)(u >> 16));
  }
  unsigned o = (unsigned)f2bf(a0) | ((unsigned)f2bf(a1) << 16);
  *(unsigned*)(acc + row * 768 + d2 * 2) = o;
}

extern "C" void kernel_launch(void* const* d_in, const int* in_sizes, int n_in,
                              void* d_out, int out_size, void* d_ws, size_t ws_size,
                              hipStream_t stream)
{
  const float* x   = (const float*)d_in[0];
  const float* lng = (const float*)d_in[1];
  const float* lnb = (const float*)d_in[2];
  const float* qw  = (const float*)d_in[3];
  const float* qb  = (const float*)d_in[4];
  const float* kw  = (const float*)d_in[5];
  const float* kb  = (const float*)d_in[6];
  const float* vw  = (const float*)d_in[7];
  const float* vb  = (const float*)d_in[8];
  const float* inw = (const float*)d_in[9];
  const float* inb = (const float*)d_in[10];
  const float* mob = (const float*)d_in[12];
  const float* ow  = (const float*)d_in[13];
  const float* ob  = (const float*)d_in[14];

  const long n1 = 589824;                 // 768*768
  char* ws = (char*)d_ws;
  size_t off = 0;
  auto alloc = [&](size_t bytes) -> char* {
    char* p = ws + off;
    off += (bytes + 255) & ~(size_t)255;
    return p;
  };
  unsigned short* Wc = (unsigned short*)alloc((size_t)5 * n1 * 2);  // Mq,Mk,Mv,mowB,owB
  float* bc = (float*)alloc(2304 * 4);
  float* zb = (float*)alloc(768 * 4);
  size_t fixed = off;

  // choose largest batch-group size g that fits ws
  int g = 0;
  const int cands[4] = {8, 4, 2, 1};
  for (int ci = 0; ci < 4; ++ci) {
    int c = cands[ci];
    size_t need = fixed + (size_t)c * 4096 * 768 * 2      // xn / acc slot
                + 2 * (size_t)c * 6063 * 768 * 2          // qp, kp
                + 1024;
    if (need <= ws_size) { g = c; break; }
  }
  if (!g) return;

  char* GR = ws + fixed;
  unsigned short* xnacc = (unsigned short*)GR;                   // g*4096 rows
  unsigned short* qp = xnacc + (size_t)g * 4096 * 768;           // g*6063 rows
  unsigned short* kp = qp + (size_t)g * 6063 * 768;              // g*6063 rows
  // staging for weight prep (dead before group 0's LN)
  unsigned short* inwB = (unsigned short*)GR;                    // 3*n1
  unsigned short* wT   = inwB + 3 * n1;                          // 3*n1

  unsigned short* mowB = Wc + 3 * n1;
  unsigned short* owB  = Wc + 4 * n1;

  // ---- weight prep (merged) ----
  mstr_prep<<<dim3(13257), dim3(256), 0, stream>>>(qw, kw, vw, inw, (const float*)d_in[11], ow,
                                                   inb, qb, kb, vb, inwB, wT, mowB, owB, bc, zb);
  mstr_gemm<0><<<dim3(36, 3), dim3(256), 0, stream>>>(inwB, 768, wT, zb, Wc, Wc, Wc,
                                                      nullptr, nullptr, 768, 768, 6, 36, n1);

  // ---- per-group pipeline ----
  int ng = 8 / g;
  for (int gi = 0; gi < ng; ++gi) {
    const float* xg = x + (long)gi * g * 4096 * 768;
    unsigned short* vp = (unsigned short*)d_out + (long)gi * g * 4096 * 768 * 2;  // scratch in d_out
    mstr_ln<<<dim3(g * 4095), dim3(256), 0, stream>>>(xg, lng, lnb, xnacc);
    int M1 = g * 4095, gb1 = (M1 + 127) / 128;
    int nwg1 = gb1 * 18;
    // fused Q/K/V projection: N=2304, segments -> qp/kp/vp with row remap
    mstr_gemm<0><<<dim3(nwg1), dim3(256), 0, stream>>>(xnacc, M1, Wc, bc,
                                                       qp, kp, vp, nullptr, nullptr,
                                                       4095, 6063, 18, nwg1, 0);
    mstr_pool<<<dim3(g * 1365, 3), dim3(384), 0, stream>>>(qp, kp, vp, 0, 4095, 1365);
    mstr_pool<<<dim3(g * 453, 3), dim3(384), 0, stream>>>(qp, kp, vp, 4095, 5460, 453);
    mstr_pool<<<dim3(g * 150, 3), dim3(384), 0, stream>>>(qp, kp, vp, 5460, 5913, 150);
    int nw = g * 2021 * 6;
    mstr_attn<<<dim3((nw + 3) / 4), dim3(256), 0, stream>>>(qp, kp, vp, nw);
    int M2 = g * 6063;
    int nwg2 = ((M2 + 127) / 128) * 6;
    // mo projection with fused exact GELU in epilogue
    mstr_gemm<2><<<dim3(nwg2), dim3(256), 0, stream>>>(qp, M2, mowB, mob, kp, kp, kp,
                                                       nullptr, nullptr, M2, 0, 6, nwg2, 0);
    mstr_gelusum<<<dim3(g * 6144), dim3(256), 0, stream>>>(kp, xnacc);
    int M3 = g * 4096;
    int nwg3 = (M3 / 128) * 6;
    mstr_gemm<1><<<dim3(nwg3), dim3(256), 0, stream>>>(xnacc, M3, owB, ob, nullptr, nullptr, nullptr,
                                                       (float*)d_out + (long)gi * g * 4096 * 768, xg,
                                                       M3, 0, 6, nwg3, 0);
  }
}